// Round 10
// baseline (459.522 us; speedup 1.0000x reference)
//
#include <hip/hip_runtime.h>

// Poisson learning, split-fp16 MFMA:
//   prep: W*32 -> Whi/Wlo fp16; samples -> fp16
//   gemm1: S = SampH@(Whi+Wlo)^T + b  (2-pass MFMA, BK=64)
//   gemm2: G = S S^T - 1e5 I  (S hi/lo 2-pass, BK=64); G SYMMETRIC =>
//   At[l][m] = exp(G[l][m]-mx[m])*inv[m]  (COLUMN stats — two-pass)
//   d == 1 in fp32 => P = A^T, Db = B0
//   5 iterations, each ONE kernel: build U(t) in LDS from prev Part(+Db,+pred)
//   [same summation order as old iter_fin], then split-K MFMA partials.
//   Final small kernel sums Part into fp32 out.

typedef _Float16 f16_t;
typedef f16_t f16x4 __attribute__((ext_vector_type(4)));
typedef f16_t f16x8 __attribute__((ext_vector_type(8)));
typedef float floatx4 __attribute__((ext_vector_type(4)));

__device__ __forceinline__ void async_copy16(const void* g, void* l) {
  __builtin_amdgcn_global_load_lds(
      (const __attribute__((address_space(1))) void*)g,
      (__attribute__((address_space(3))) void*)l, 16, 0, 0);
}

__device__ __forceinline__ f16_t hi_of(float x) { return (f16_t)x; }
__device__ __forceinline__ f16_t lo_of(float x, f16_t h) {
  return (f16_t)(x - (float)h);
}

// blocks [0,3072): W*32 -> hi/lo.  blocks [3072,27648): samples -> fp16
__global__ __launch_bounds__(256) void prep_kernel(
    const float* __restrict__ W, f16_t* __restrict__ Whi, f16_t* __restrict__ Wlo,
    const float* __restrict__ samples, f16_t* __restrict__ SampH)
{
  const int bx = blockIdx.x, tid = threadIdx.x;
  if (bx < 3072) {
    const int i = bx * 256 + tid;
    float4 v = ((const float4*)W)[i];
    v.x *= 32.f; v.y *= 32.f; v.z *= 32.f; v.w *= 32.f;
    f16x4 h, l;
    f16_t h0 = hi_of(v.x); h[0] = h0; l[0] = lo_of(v.x, h0);
    f16_t h1 = hi_of(v.y); h[1] = h1; l[1] = lo_of(v.y, h1);
    f16_t h2 = hi_of(v.z); h[2] = h2; l[2] = lo_of(v.z, h2);
    f16_t h3 = hi_of(v.w); h[3] = h3; l[3] = lo_of(v.w, h3);
    *(f16x4*)(Whi + (size_t)i * 4) = h;
    *(f16x4*)(Wlo + (size_t)i * 4) = l;
  } else {
    const int i = (bx - 3072) * 256 + tid;
    const float4 v = ((const float4*)samples)[i];
    f16x4 h;
    h[0] = (f16_t)v.x; h[1] = (f16_t)v.y; h[2] = (f16_t)v.z; h[3] = (f16_t)v.w;
    *(f16x4*)(SampH + (size_t)i * 4) = h;
  }
}

// NT GEMM: C[m,n] = sum_k A[m,k]*(Bhi+Blo)[n,k], BK=64 two-plane staging.
// CMODE 0: C -> *cscale + bias, split-store Chi/Clo.  CMODE 1: fp32, -1e5 diag.
template <int CMODE>
__global__ __launch_bounds__(256) void gemm_mfma(
    const f16_t* __restrict__ AhiG,
    const f16_t* __restrict__ BhiG, const f16_t* __restrict__ BloG,
    const float* __restrict__ bias,
    float* __restrict__ Cf, f16_t* __restrict__ Chi, f16_t* __restrict__ Clo,
    int M, int N, int K, long long sA, long long sB, long long sC, float cscale)
{
  AhiG += (long long)blockIdx.z * sA;
  BhiG += (long long)blockIdx.z * sB;
  BloG += (long long)blockIdx.z * sB;
  if (CMODE == 1) Cf += (long long)blockIdx.z * sC;

  __shared__ __align__(16) f16_t AsHi[2 * 128 * 32];
  __shared__ __align__(16) f16_t BsHi[2 * 128 * 32];
  __shared__ __align__(16) f16_t BsLo[2 * 128 * 32];

  const int tid = threadIdx.x;
  const int lane = tid & 63;
  const int wave = tid >> 6;
  const int wm = wave >> 1, wn = wave & 1;
  const int m0 = blockIdx.y * 128;
  const int n0 = blockIdx.x * 128;

  const int fr = lane & 15;
  const int kg = (lane >> 4) * 8;
  const int aoff = (wm * 64 + fr) * 32 + kg;
  const int boff = (wn * 64 + fr) * 32 + kg;

  floatx4 acc[4][4] = {};

  for (int k0 = 0; k0 < K; k0 += 64) {
    __syncthreads();
#pragma unroll
    for (int it = 0; it < 4; ++it) {
      const int cb = it * 256 + wave * 64;   // wave-uniform chunk base
      const int c = cb + lane;
      const int kk = c >> 9;                  // k-plane 0/1 (wave-uniform)
      const int row = (c >> 2) & 127;
      const int kc = kk * 32 + (c & 3) * 8;
      const size_t ga = (size_t)(m0 + row) * K + k0 + kc;
      const size_t gb = (size_t)(n0 + row) * K + k0 + kc;
      async_copy16(AhiG + ga, (char*)AsHi + (size_t)cb * 16);
      async_copy16(BhiG + gb, (char*)BsHi + (size_t)cb * 16);
      async_copy16(BloG + gb, (char*)BsLo + (size_t)cb * 16);
    }
    __syncthreads();

#pragma unroll
    for (int kk = 0; kk < 2; ++kk) {
      f16x8 ah[4], bh[4], bl[4];
#pragma unroll
      for (int t = 0; t < 4; ++t) {
        ah[t] = *(const f16x8*)&AsHi[kk * 4096 + aoff + t * 512];
        bh[t] = *(const f16x8*)&BsHi[kk * 4096 + boff + t * 512];
        bl[t] = *(const f16x8*)&BsLo[kk * 4096 + boff + t * 512];
      }
#pragma unroll
      for (int i = 0; i < 4; ++i)
#pragma unroll
        for (int j = 0; j < 4; ++j) {
          acc[i][j] = __builtin_amdgcn_mfma_f32_16x16x32_f16(ah[i], bh[j], acc[i][j], 0, 0, 0);
          acc[i][j] = __builtin_amdgcn_mfma_f32_16x16x32_f16(ah[i], bl[j], acc[i][j], 0, 0, 0);
        }
    }
  }

  const int mr = (lane >> 4) * 4;
#pragma unroll
  for (int j = 0; j < 4; ++j) {
    const int n = n0 + wn * 64 + j * 16 + fr;
    const float bj = (CMODE == 0) ? bias[n] : 0.f;
#pragma unroll
    for (int i = 0; i < 4; ++i) {
#pragma unroll
      for (int r = 0; r < 4; ++r) {
        const int m = m0 + wm * 64 + i * 16 + mr + r;
        float v = acc[i][j][r];
        if (CMODE == 0) {
          v = v * cscale + bj;
          f16_t h = hi_of(v);
          Chi[(size_t)m * N + n] = h;
          Clo[(size_t)m * N + n] = lo_of(v, h);
        } else {
          if (m == n) v -= 1e5f;
          Cf[(size_t)m * N + n] = v;
        }
      }
    }
  }
}

// per-row max and 1/sum(exp(g-max)) of G; one block per global row
__global__ __launch_bounds__(256) void rowstats_kernel(
    const float* __restrict__ G, float* __restrict__ mx, float* __restrict__ inv)
{
  __shared__ float red[4];
  const int tid = threadIdx.x;
  const float* g = G + (size_t)blockIdx.x * 1024;
  const float4 v = ((const float4*)g)[tid];

  float m = fmaxf(fmaxf(v.x, v.y), fmaxf(v.z, v.w));
#pragma unroll
  for (int off = 32; off > 0; off >>= 1) m = fmaxf(m, __shfl_down(m, off));
  if ((tid & 63) == 0) red[tid >> 6] = m;
  __syncthreads();
  m = fmaxf(fmaxf(red[0], red[1]), fmaxf(red[2], red[3]));
  __syncthreads();

  float s = __expf(v.x - m) + __expf(v.y - m) + __expf(v.z - m) + __expf(v.w - m);
#pragma unroll
  for (int off = 32; off > 0; off >>= 1) s += __shfl_down(s, off);
  if ((tid & 63) == 0) red[tid >> 6] = s;
  __syncthreads();
  if (tid == 0) {
    mx[blockIdx.x] = m;
    inv[blockIdx.x] = 1.0f / (red[0] + red[1] + red[2] + red[3]);
  }
}

// At[l][m] = exp(G[l][m] - mx[m]) * inv[m]  (COLUMN stats; valid since G sym)
__global__ __launch_bounds__(256) void make_at_kernel(
    const float* __restrict__ G, const float* __restrict__ mx,
    const float* __restrict__ inv, f16_t* __restrict__ At)
{
  const int row = blockIdx.x;
  const int b = row >> 10;
  const int tid = threadIdx.x;
  const float4 g = ((const float4*)(G + (size_t)row * 1024))[tid];
  const float4 m = ((const float4*)(mx + b * 1024))[tid];
  const float4 iv = ((const float4*)(inv + b * 1024))[tid];
  f16x4 o;
  o[0] = (f16_t)(__expf(g.x - m.x) * iv.x);
  o[1] = (f16_t)(__expf(g.y - m.y) * iv.y);
  o[2] = (f16_t)(__expf(g.z - m.z) * iv.z);
  o[3] = (f16_t)(__expf(g.w - m.w) * iv.w);
  *(f16x4*)(At + (size_t)row * 1024 + tid * 4) = o;
}

// Db = (sup - avg) * row_has, plus DbT fp16; one block (1024 thr) per batch
__global__ __launch_bounds__(1024) void make_db_kernel(
    const float* __restrict__ sup, float* __restrict__ Db, f16_t* __restrict__ DbT)
{
  const int L = 1024, Nn = 64;
  const float* s = sup + (size_t)blockIdx.x * L * Nn;
  float* db = Db + (size_t)blockIdx.x * L * Nn;
  f16_t* dbt = DbT + (size_t)blockIdx.x * L * Nn;
  __shared__ float rowhas[1024];
  __shared__ float cpart[1024];
  __shared__ float tpart[16];
  __shared__ float avg[64];
  __shared__ float totalsh;
  const int tid = threadIdx.x;

  const float4* sr = (const float4*)(s + (size_t)tid * 64);
  float ss = 0.f;
#pragma unroll
  for (int i = 0; i < 16; ++i) { const float4 v = sr[i]; ss += (v.x + v.y) + (v.z + v.w); }
  const float rh = (ss > 0.5f) ? 1.f : 0.f;
  rowhas[tid] = rh;
  float t = rh;
#pragma unroll
  for (int off = 32; off > 0; off >>= 1) t += __shfl_down(t, off);
  if ((tid & 63) == 0) tpart[tid >> 6] = t;

  const int n = tid & 63, seg = tid >> 6;
  float cs = 0.f;
  for (int l = seg * 64; l < seg * 64 + 64; ++l) cs += s[(size_t)l * 64 + n];
  cpart[seg * 64 + n] = cs;
  __syncthreads();
  if (tid == 0) { float tt = 0.f; for (int i = 0; i < 16; ++i) tt += tpart[i]; totalsh = tt; }
  __syncthreads();
  if (tid < 64) {
    float a = 0.f;
    for (int i = 0; i < 16; ++i) a += cpart[i * 64 + tid];
    avg[tid] = a / totalsh;
  }
  __syncthreads();

  const float4* s4 = (const float4*)s;
  float4* d4 = (float4*)db;
  for (int i = tid; i < (L * Nn) / 4; i += 1024) {
    float4 v = s4[i];
    const int l = i >> 4;
    const int nb = (i & 15) * 4;
    const float rhl = rowhas[l];
    v.x = (v.x - avg[nb + 0]) * rhl;
    v.y = (v.y - avg[nb + 1]) * rhl;
    v.z = (v.z - avg[nb + 2]) * rhl;
    v.w = (v.w - avg[nb + 3]) * rhl;
    d4[i] = v;
  }
  // DbT[n][l] = (f16)Db[l][n]
  for (int i = tid; i < L * Nn; i += 1024) {
    const int n2 = i >> 10, l2 = i & 1023;
    dbt[i] = (f16_t)((s[(size_t)l2 * 64 + n2] - avg[n2]) * rowhas[l2]);
  }
}

// One power-iteration step (fused fin-of-previous + split-K partial):
//   Build U(t)[l'][n] for l' in ks-quarter: FIRST ? DbT : sum Part(prev)+Db(+pred)
//   [exact iter_fin summation order], transposed into LDS UtFull fp16.
//   Then Part[ks][b][l][n] = sum_{m in quarter} At[l][m] * U(t)[m][n].
// grid (16 l-tiles, 8 batches, 4 k-splits), 256 threads.
template <int FIRST, int PRED>
__global__ __launch_bounds__(256) void iter_step(
    const f16_t* __restrict__ At, const f16_t* __restrict__ DbT,
    const float* __restrict__ PartPrev, const float* __restrict__ Db,
    const float* __restrict__ Pred, float* __restrict__ PartOut)
{
  const int L = 1024, Nn = 64;
  const int b = blockIdx.y, l0 = blockIdx.x * 64, ks = blockIdx.z;
  At += (size_t)b * L * L;
  PartOut += (((size_t)ks * 8 + b) * L) * Nn;

  __shared__ __align__(16) f16_t AtS[2 * 64 * 32];
  __shared__ __align__(16) f16_t UtFull[64 * 264];  // [n][l' local], +8 pad

  const int tid = threadIdx.x;
  const int lane = tid & 63;
  const int wave = tid >> 6;
  const int fr = lane & 15;
  const int kg = (lane >> 4) * 8;

  // ---- build U(t) quarter in LDS
  if (FIRST) {
    const f16_t* dbt = DbT + (size_t)b * Nn * L + ks * 256;
#pragma unroll
    for (int it = 0; it < 8; ++it) {
      const int idx = it * 256 + tid;            // of 2048 8-elem chunks
      const int n = idx >> 5, lc = (idx & 31) * 8;
      *(f16x8*)&UtFull[n * 264 + lc] = *(const f16x8*)(dbt + (size_t)n * L + lc);
    }
  } else {
    const size_t base = ((size_t)b * L + ks * 256) * Nn;
    const size_t ksS = (size_t)8 * L * Nn;
#pragma unroll
    for (int it = 0; it < 16; ++it) {
      const int idx = it * 256 + tid;            // of 4096 float4 chunks
      const int lql = idx >> 4, n4 = (idx & 15) * 4;
      const size_t o = base + (size_t)lql * Nn + n4;
      float4 v = *(const float4*)(PartPrev + o);
      const float4 p1 = *(const float4*)(PartPrev + o + ksS);
      const float4 p2 = *(const float4*)(PartPrev + o + 2 * ksS);
      const float4 p3 = *(const float4*)(PartPrev + o + 3 * ksS);
      v.x += p1.x; v.y += p1.y; v.z += p1.z; v.w += p1.w;
      v.x += p2.x; v.y += p2.y; v.z += p2.z; v.w += p2.w;
      v.x += p3.x; v.y += p3.y; v.z += p3.z; v.w += p3.w;
      const float4 d = *(const float4*)(Db + o);
      v.x += d.x; v.y += d.y; v.z += d.z; v.w += d.w;
      if (PRED) {
        const float4 p = *(const float4*)(Pred + o);
        v.x += p.x; v.y += p.y; v.z += p.z; v.w += p.w;
      }
      UtFull[(n4 + 0) * 264 + lql] = (f16_t)v.x;
      UtFull[(n4 + 1) * 264 + lql] = (f16_t)v.y;
      UtFull[(n4 + 2) * 264 + lql] = (f16_t)v.z;
      UtFull[(n4 + 3) * 264 + lql] = (f16_t)v.w;
    }
  }

  floatx4 acc[4] = {};

  for (int mi = 0; mi < 4; ++mi) {
    const int m0 = ks * 256 + mi * 64;
    __syncthreads();
#pragma unroll
    for (int it = 0; it < 2; ++it) {
      const int cb = it * 256 + wave * 64;  // wave-uniform
      const int c = cb + lane;
      const int kk = c >> 8;
      const int row = (c >> 2) & 63;
      const int kc = kk * 32 + (c & 3) * 8;
      async_copy16(At + (size_t)(l0 + row) * L + m0 + kc, (char*)AtS + (size_t)cb * 16);
    }
    __syncthreads();
#pragma unroll
    for (int kk = 0; kk < 2; ++kk) {
      const f16x8 a = *(const f16x8*)&AtS[kk * 2048 + (wave * 16 + fr) * 32 + kg];
      const int uoff = mi * 64 + kk * 32 + kg;
#pragma unroll
      for (int j = 0; j < 4; ++j) {
        const f16x8 bf = *(const f16x8*)&UtFull[(j * 16 + fr) * 264 + uoff];
        acc[j] = __builtin_amdgcn_mfma_f32_16x16x32_f16(a, bf, acc[j], 0, 0, 0);
      }
    }
  }

  const int mr = (lane >> 4) * 4;
#pragma unroll
  for (int j = 0; j < 4; ++j) {
    const int n = j * 16 + fr;
#pragma unroll
    for (int r = 0; r < 4; ++r) {
      const int l = wave * 16 + mr + r;
      PartOut[(size_t)(l0 + l) * Nn + n] = acc[j][r];
    }
  }
}

// Final: out = sum 4 partials + Db (fp32). grid (16 l-tiles, 8 batches).
__global__ __launch_bounds__(256) void final_fin(
    const float* __restrict__ Part, const float* __restrict__ Db,
    float* __restrict__ OutF)
{
  const int L = 1024, Nn = 64;
  const int b = blockIdx.y, l0 = blockIdx.x * 64;
  const size_t base = ((size_t)b * L + l0) * Nn;
  const size_t ksS = (size_t)8 * L * Nn;
  const int tid = threadIdx.x;

#pragma unroll
  for (int it = 0; it < 4; ++it) {
    const int idx = it * 256 + tid;
    const int l = idx >> 4, n4 = (idx & 15) * 4;
    const size_t o = base + (size_t)l * Nn + n4;
    float4 v = *(const float4*)(Part + o);
    const float4 p1 = *(const float4*)(Part + o + ksS);
    const float4 p2 = *(const float4*)(Part + o + 2 * ksS);
    const float4 p3 = *(const float4*)(Part + o + 3 * ksS);
    v.x += p1.x; v.y += p1.y; v.z += p1.z; v.w += p1.w;
    v.x += p2.x; v.y += p2.y; v.z += p2.z; v.w += p2.w;
    v.x += p3.x; v.y += p3.y; v.z += p3.z; v.w += p3.w;
    const float4 d = *(const float4*)(Db + o);
    v.x += d.x; v.y += d.y; v.z += d.z; v.w += d.w;
    *(float4*)(OutF + o) = v;
  }
}

extern "C" void kernel_launch(void* const* d_in, const int* in_sizes, int n_in,
                              void* d_out, int out_size, void* d_ws, size_t ws_size,
                              hipStream_t stream) {
  const float* samples = (const float*)d_in[0];  // [8,1024,3072]
  const float* label   = (const float*)d_in[1];  // [8,1024,64]
  const float* predict = (const float*)d_in[2];  // [8,1024,64]
  const float* W       = (const float*)d_in[3];  // [1024,3072]
  const float* bproj   = (const float*)d_in[4];  // [1024]
  float* out = (float*)d_out;                    // [8,1024,64]

  char* ws = (char*)d_ws;
  // region A [0, 12.58 MB): Whi/Wlo during projection; small buffers after
  f16_t* Whi = (f16_t*)ws;
  f16_t* Wlo = (f16_t*)(ws + 6291456);
  float* mx  = (float*)ws;                       // after gemm1 (W dead)
  float* inv = (float*)(ws + 32768);
  float* Db  = (float*)(ws + 65536);             // 2 MB
  f16_t* DbT = (f16_t*)(ws + 65536 + 2097152);   // 1 MB
  // region B [12.58, 62.9 MB): SampH (50 MB) during gemm1; G (32 MB) after
  f16_t* SampH = (f16_t*)(ws + 12582912);
  float* G     = (float*)(ws + 12582912);
  // region C [62.9, 96.5 MB): Shi/Slo; At aliases Shi; PartA/PartB alias Slo
  f16_t* Shi = (f16_t*)(ws + 62914560);
  f16_t* Slo = (f16_t*)(ws + 62914560 + 16777216);
  f16_t* At  = Shi;
  float* PartA = (float*)Slo;                    // 8 MB (Slo dead after gemm2)
  float* PartB = (float*)(ws + 62914560 + 16777216 + 8388608);  // 8 MB

  const long long LH = 1024LL * 1024;
  const long long LL = 1024LL * 1024;

  // 0) prep: W split + samples convert (fused)
  prep_kernel<<<dim3(27648), 256, 0, stream>>>(W, Whi, Wlo, samples, SampH);

  // 1) S = samples @ W^T + b; epilogue x(1/32)+bias, split-store hi/lo
  gemm_mfma<0><<<dim3(8, 64, 1), 256, 0, stream>>>(
      SampH, Whi, Wlo, bproj, nullptr, Shi, Slo,
      8192, 1024, 3072, 0, 0, 0, 1.0f / 32.0f);

  // 2) G = S S^T - 1e5 I per batch (overwrites SampH region — dead)
  gemm_mfma<1><<<dim3(8, 8, 8), 256, 0, stream>>>(
      Shi, Shi, Slo, nullptr, G, nullptr, nullptr,
      1024, 1024, 1024, LH, LH, LL, 1.0f);

  // 3) row stats, then At = softmax^T fp16 with column stats (Shi dead)
  rowstats_kernel<<<8192, 256, 0, stream>>>(G, mx, inv);
  make_at_kernel<<<8192, 256, 0, stream>>>(G, mx, inv, At);

  // 4) Db fp32 + DbT fp16 (fused)
  make_db_kernel<<<8, 1024, 0, stream>>>(label, Db, DbT);

  // 5) power iteration: 5 fused step kernels + final reduce
  dim3 gp(16, 8, 4), gf(16, 8);
  iter_step<1, 0><<<gp, 256, 0, stream>>>(At, DbT, nullptr, Db, nullptr, PartA); // ut2
  iter_step<0, 0><<<gp, 256, 0, stream>>>(At, nullptr, PartA, Db, nullptr, PartB); // ut3 (U=ut2)
  iter_step<0, 1><<<gp, 256, 0, stream>>>(At, nullptr, PartB, Db, predict, PartA); // ut4 (U=ut3+pred)
  iter_step<0, 0><<<gp, 256, 0, stream>>>(At, nullptr, PartA, Db, nullptr, PartB); // ut5 (U=ut4)
  iter_step<0, 0><<<gp, 256, 0, stream>>>(At, nullptr, PartB, Db, nullptr, PartA); // ut6 (U=ut5)
  final_fin<<<gf, 256, 0, stream>>>(PartA, Db, out);                               // out=ut6
}

// Round 12
// 419.564 us; speedup vs baseline: 1.0952x; 1.0952x over previous
//
#include <hip/hip_runtime.h>

// Poisson learning, split-fp16 MFMA:
//   prep: W*32 -> Whi/Wlo fp16; samples -> fp16
//   gemm1: S = SampH@(Whi+Wlo)^T + b  (2-pass MFMA, BK=64)
//   gemm2: G = S S^T - 1e5 I, LOWER-TRIANGLE tiles only (36 pairs/batch);
//          off-diag tiles mirrored via LDS transpose (G made exactly symmetric)
//   At[l][m] = exp(G[l][m]-mx[m])*inv[m]  (COLUMN stats — two-pass)
//   d == 1 in fp32 => P = A^T, Db = B0
//   5 iterations: split-K MFMA partials + finalize (UT fp16 between steps).

typedef _Float16 f16_t;
typedef f16_t f16x4 __attribute__((ext_vector_type(4)));
typedef f16_t f16x8 __attribute__((ext_vector_type(8)));
typedef float floatx4 __attribute__((ext_vector_type(4)));

__device__ __forceinline__ void async_copy16(const void* g, void* l) {
  __builtin_amdgcn_global_load_lds(
      (const __attribute__((address_space(1))) void*)g,
      (__attribute__((address_space(3))) void*)l, 16, 0, 0);
}

__device__ __forceinline__ f16_t hi_of(float x) { return (f16_t)x; }
__device__ __forceinline__ f16_t lo_of(float x, f16_t h) {
  return (f16_t)(x - (float)h);
}

// blocks [0,3072): W*32 -> hi/lo.  blocks [3072,27648): samples -> fp16
__global__ __launch_bounds__(256) void prep_kernel(
    const float* __restrict__ W, f16_t* __restrict__ Whi, f16_t* __restrict__ Wlo,
    const float* __restrict__ samples, f16_t* __restrict__ SampH)
{
  const int bx = blockIdx.x, tid = threadIdx.x;
  if (bx < 3072) {
    const int i = bx * 256 + tid;
    float4 v = ((const float4*)W)[i];
    v.x *= 32.f; v.y *= 32.f; v.z *= 32.f; v.w *= 32.f;
    f16x4 h, l;
    f16_t h0 = hi_of(v.x); h[0] = h0; l[0] = lo_of(v.x, h0);
    f16_t h1 = hi_of(v.y); h[1] = h1; l[1] = lo_of(v.y, h1);
    f16_t h2 = hi_of(v.z); h[2] = h2; l[2] = lo_of(v.z, h2);
    f16_t h3 = hi_of(v.w); h[3] = h3; l[3] = lo_of(v.w, h3);
    *(f16x4*)(Whi + (size_t)i * 4) = h;
    *(f16x4*)(Wlo + (size_t)i * 4) = l;
  } else {
    const int i = (bx - 3072) * 256 + tid;
    const float4 v = ((const float4*)samples)[i];
    f16x4 h;
    h[0] = (f16_t)v.x; h[1] = (f16_t)v.y; h[2] = (f16_t)v.z; h[3] = (f16_t)v.w;
    *(f16x4*)(SampH + (size_t)i * 4) = h;
  }
}

// NT GEMM: C[m,n] = sum_k A[m,k]*(Bhi+Blo)[n,k], BK=64 two-plane staging.
// CMODE 0: rectangular grid; C -> *cscale + bias, split-store Chi/Clo.
// CMODE 1: triangular grid (blockIdx.x = pair idx of 36); fp32 C, -1e5 diag;
//          off-diag tiles also write the mirrored tile via LDS transpose.
template <int CMODE>
__global__ __launch_bounds__(256) void gemm_mfma(
    const f16_t* __restrict__ AhiG,
    const f16_t* __restrict__ BhiG, const f16_t* __restrict__ BloG,
    const float* __restrict__ bias,
    float* __restrict__ Cf, f16_t* __restrict__ Chi, f16_t* __restrict__ Clo,
    int M, int N, int K, long long sA, long long sB, long long sC, float cscale)
{
  AhiG += (long long)blockIdx.z * sA;
  BhiG += (long long)blockIdx.z * sB;
  BloG += (long long)blockIdx.z * sB;
  if (CMODE == 1) Cf += (long long)blockIdx.z * sC;

  // unified LDS: 3 staging planes of 16384 B each (f16 = 2 B!);
  // CMODE1 epilogue reuses the front as a 128x36 fp32 transpose (18432 B).
  __shared__ __align__(16) char smem[49152];
  f16_t* AsHi = (f16_t*)smem;
  f16_t* BsHi = (f16_t*)(smem + 16384);
  f16_t* BsLo = (f16_t*)(smem + 32768);

  const int tid = threadIdx.x;
  const int lane = tid & 63;
  const int wave = tid >> 6;
  const int wm = wave >> 1, wn = wave & 1;

  int m0, n0;
  if (CMODE == 0) {
    m0 = blockIdx.y * 128;
    n0 = blockIdx.x * 128;
  } else {
    // triangular pair mapping: idx -> (i >= j)
    int idx = blockIdx.x, i = 0, accu = 0;
    while (accu + i + 1 <= idx) { accu += i + 1; ++i; }
    m0 = i * 128;
    n0 = (idx - accu) * 128;
  }

  const int fr = lane & 15;
  const int kg = (lane >> 4) * 8;
  const int aoff = (wm * 64 + fr) * 32 + kg;
  const int boff = (wn * 64 + fr) * 32 + kg;

  floatx4 acc[4][4] = {};

  for (int k0 = 0; k0 < K; k0 += 64) {
    __syncthreads();
#pragma unroll
    for (int it = 0; it < 4; ++it) {
      const int cb = it * 256 + wave * 64;   // wave-uniform chunk base
      const int c = cb + lane;
      const int kk = c >> 9;                  // k-plane 0/1 (wave-uniform)
      const int row = (c >> 2) & 127;
      const int kc = kk * 32 + (c & 3) * 8;
      const size_t ga = (size_t)(m0 + row) * K + k0 + kc;
      const size_t gb = (size_t)(n0 + row) * K + k0 + kc;
      async_copy16(AhiG + ga, (char*)AsHi + (size_t)cb * 16);
      async_copy16(BhiG + gb, (char*)BsHi + (size_t)cb * 16);
      async_copy16(BloG + gb, (char*)BsLo + (size_t)cb * 16);
    }
    __syncthreads();

#pragma unroll
    for (int kk = 0; kk < 2; ++kk) {
      f16x8 ah[4], bh[4], bl[4];
#pragma unroll
      for (int t = 0; t < 4; ++t) {
        ah[t] = *(const f16x8*)&AsHi[kk * 4096 + aoff + t * 512];
        bh[t] = *(const f16x8*)&BsHi[kk * 4096 + boff + t * 512];
        bl[t] = *(const f16x8*)&BsLo[kk * 4096 + boff + t * 512];
      }
#pragma unroll
      for (int i = 0; i < 4; ++i)
#pragma unroll
        for (int j = 0; j < 4; ++j) {
          acc[i][j] = __builtin_amdgcn_mfma_f32_16x16x32_f16(ah[i], bh[j], acc[i][j], 0, 0, 0);
          acc[i][j] = __builtin_amdgcn_mfma_f32_16x16x32_f16(ah[i], bl[j], acc[i][j], 0, 0, 0);
        }
    }
  }

  const int mr = (lane >> 4) * 4;
#pragma unroll
  for (int j = 0; j < 4; ++j) {
    const int n = n0 + wn * 64 + j * 16 + fr;
    const float bj = (CMODE == 0) ? bias[n] : 0.f;
#pragma unroll
    for (int i = 0; i < 4; ++i) {
#pragma unroll
      for (int r = 0; r < 4; ++r) {
        const int m = m0 + wm * 64 + i * 16 + mr + r;
        float v = acc[i][j][r];
        if (CMODE == 0) {
          v = v * cscale + bj;
          f16_t h = hi_of(v);
          Chi[(size_t)m * N + n] = h;
          Clo[(size_t)m * N + n] = lo_of(v, h);
        } else {
          if (m == n) v -= 1e5f;
          Cf[(size_t)m * N + n] = v;
        }
      }
    }
  }

  // mirror epilogue: write G[n][m] = computed C[m][n] for off-diag tiles
  if (CMODE == 1 && m0 != n0) {
    float* T = (float*)smem;            // 128 x (stride 36) fp32 = 18432 B
#pragma unroll
    for (int mc = 0; mc < 4; ++mc) {    // 32-wide m-local chunks
      __syncthreads();
      if (wm == (mc >> 1)) {
        const int ibase = (mc & 1) * 2;
#pragma unroll
        for (int di = 0; di < 2; ++di) {
#pragma unroll
          for (int j = 0; j < 4; ++j) {
            const int nl = wn * 64 + j * 16 + fr;       // local col
#pragma unroll
            for (int r = 0; r < 4; ++r) {
              const int mloc = di * 16 + mr + r;        // within chunk
              T[nl * 36 + mloc] = acc[ibase + di][j][r];
            }
          }
        }
      }
      __syncthreads();
      const int row = tid >> 1, half = tid & 1;
      const float* src = &T[row * 36 + half * 16];
      float* dst = Cf + (size_t)(n0 + row) * N + m0 + mc * 32 + half * 16;
#pragma unroll
      for (int q = 0; q < 16; ++q) dst[q] = src[q];
    }
  }
}

// per-row max and 1/sum(exp(g-max)) of G; one block per global row
__global__ __launch_bounds__(256) void rowstats_kernel(
    const float* __restrict__ G, float* __restrict__ mx, float* __restrict__ inv)
{
  __shared__ float red[4];
  const int tid = threadIdx.x;
  const float* g = G + (size_t)blockIdx.x * 1024;
  const float4 v = ((const float4*)g)[tid];

  float m = fmaxf(fmaxf(v.x, v.y), fmaxf(v.z, v.w));
#pragma unroll
  for (int off = 32; off > 0; off >>= 1) m = fmaxf(m, __shfl_down(m, off));
  if ((tid & 63) == 0) red[tid >> 6] = m;
  __syncthreads();
  m = fmaxf(fmaxf(red[0], red[1]), fmaxf(red[2], red[3]));
  __syncthreads();

  float s = __expf(v.x - m) + __expf(v.y - m) + __expf(v.z - m) + __expf(v.w - m);
#pragma unroll
  for (int off = 32; off > 0; off >>= 1) s += __shfl_down(s, off);
  if ((tid & 63) == 0) red[tid >> 6] = s;
  __syncthreads();
  if (tid == 0) {
    mx[blockIdx.x] = m;
    inv[blockIdx.x] = 1.0f / (red[0] + red[1] + red[2] + red[3]);
  }
}

// At[l][m] = exp(G[l][m] - mx[m]) * inv[m]  (COLUMN stats; valid since G sym)
__global__ __launch_bounds__(256) void make_at_kernel(
    const float* __restrict__ G, const float* __restrict__ mx,
    const float* __restrict__ inv, f16_t* __restrict__ At)
{
  const int row = blockIdx.x;
  const int b = row >> 10;
  const int tid = threadIdx.x;
  const float4 g = ((const float4*)(G + (size_t)row * 1024))[tid];
  const float4 m = ((const float4*)(mx + b * 1024))[tid];
  const float4 iv = ((const float4*)(inv + b * 1024))[tid];
  f16x4 o;
  o[0] = (f16_t)(__expf(g.x - m.x) * iv.x);
  o[1] = (f16_t)(__expf(g.y - m.y) * iv.y);
  o[2] = (f16_t)(__expf(g.z - m.z) * iv.z);
  o[3] = (f16_t)(__expf(g.w - m.w) * iv.w);
  *(f16x4*)(At + (size_t)row * 1024 + tid * 4) = o;
}

// Db = (sup - avg) * row_has, plus DbT fp16; one block (1024 thr) per batch
__global__ __launch_bounds__(1024) void make_db_kernel(
    const float* __restrict__ sup, float* __restrict__ Db, f16_t* __restrict__ DbT)
{
  const int L = 1024, Nn = 64;
  const float* s = sup + (size_t)blockIdx.x * L * Nn;
  float* db = Db + (size_t)blockIdx.x * L * Nn;
  f16_t* dbt = DbT + (size_t)blockIdx.x * L * Nn;
  __shared__ float rowhas[1024];
  __shared__ float cpart[1024];
  __shared__ float tpart[16];
  __shared__ float avg[64];
  __shared__ float totalsh;
  const int tid = threadIdx.x;

  const float4* sr = (const float4*)(s + (size_t)tid * 64);
  float ss = 0.f;
#pragma unroll
  for (int i = 0; i < 16; ++i) { const float4 v = sr[i]; ss += (v.x + v.y) + (v.z + v.w); }
  const float rh = (ss > 0.5f) ? 1.f : 0.f;
  rowhas[tid] = rh;
  float t = rh;
#pragma unroll
  for (int off = 32; off > 0; off >>= 1) t += __shfl_down(t, off);
  if ((tid & 63) == 0) tpart[tid >> 6] = t;

  const int n = tid & 63, seg = tid >> 6;
  float cs = 0.f;
  for (int l = seg * 64; l < seg * 64 + 64; ++l) cs += s[(size_t)l * 64 + n];
  cpart[seg * 64 + n] = cs;
  __syncthreads();
  if (tid == 0) { float tt = 0.f; for (int i = 0; i < 16; ++i) tt += tpart[i]; totalsh = tt; }
  __syncthreads();
  if (tid < 64) {
    float a = 0.f;
    for (int i = 0; i < 16; ++i) a += cpart[i * 64 + tid];
    avg[tid] = a / totalsh;
  }
  __syncthreads();

  const float4* s4 = (const float4*)s;
  float4* d4 = (float4*)db;
  for (int i = tid; i < (L * Nn) / 4; i += 1024) {
    float4 v = s4[i];
    const int l = i >> 4;
    const int nb = (i & 15) * 4;
    const float rhl = rowhas[l];
    v.x = (v.x - avg[nb + 0]) * rhl;
    v.y = (v.y - avg[nb + 1]) * rhl;
    v.z = (v.z - avg[nb + 2]) * rhl;
    v.w = (v.w - avg[nb + 3]) * rhl;
    d4[i] = v;
  }
  // DbT[n][l] = (f16)Db[l][n]
  for (int i = tid; i < L * Nn; i += 1024) {
    const int n2 = i >> 10, l2 = i & 1023;
    dbt[i] = (f16_t)((s[(size_t)l2 * 64 + n2] - avg[n2]) * rowhas[l2]);
  }
}

// Partial of one power-iteration step:
//   Part[ks][b][l][n] = sum_{m in ks-quarter} At[l][m] * UT[n][m]
// grid (16 l-tiles, 8 batches, 4 k-splits), 256 threads.
__global__ __launch_bounds__(256) void iter_part(
    const f16_t* __restrict__ At, const f16_t* __restrict__ UT,
    float* __restrict__ Part)
{
  const int L = 1024, Nn = 64;
  const int b = blockIdx.y, l0 = blockIdx.x * 64, ks = blockIdx.z;
  At += (size_t)b * L * L;
  UT += (size_t)b * Nn * L;
  Part += (((size_t)ks * 8 + b) * L) * Nn;

  __shared__ __align__(16) f16_t AtS[2 * 64 * 32];
  __shared__ __align__(16) f16_t UtS[2 * 64 * 32];

  const int tid = threadIdx.x;
  const int lane = tid & 63;
  const int wave = tid >> 6;
  const int fr = lane & 15;
  const int kg = (lane >> 4) * 8;

  floatx4 acc[4] = {};

  for (int mi = 0; mi < 4; ++mi) {
    const int m0 = ks * 256 + mi * 64;
    __syncthreads();
#pragma unroll
    for (int it = 0; it < 2; ++it) {
      const int cb = it * 256 + wave * 64;  // wave-uniform
      const int c = cb + lane;
      const int kk = c >> 8;
      const int row = (c >> 2) & 63;
      const int kc = kk * 32 + (c & 3) * 8;
      async_copy16(At + (size_t)(l0 + row) * L + m0 + kc, (char*)AtS + (size_t)cb * 16);
      async_copy16(UT + (size_t)row * L + m0 + kc, (char*)UtS + (size_t)cb * 16);
    }
    __syncthreads();
#pragma unroll
    for (int kk = 0; kk < 2; ++kk) {
      const f16x8 a = *(const f16x8*)&AtS[kk * 2048 + (wave * 16 + fr) * 32 + kg];
#pragma unroll
      for (int j = 0; j < 4; ++j) {
        const f16x8 bf = *(const f16x8*)&UtS[kk * 2048 + (j * 16 + fr) * 32 + kg];
        acc[j] = __builtin_amdgcn_mfma_f32_16x16x32_f16(a, bf, acc[j], 0, 0, 0);
      }
    }
  }

  const int mr = (lane >> 4) * 4;
#pragma unroll
  for (int j = 0; j < 4; ++j) {
    const int n = j * 16 + fr;
#pragma unroll
    for (int r = 0; r < 4; ++r) {
      const int l = wave * 16 + mr + r;
      Part[(size_t)(l0 + l) * Nn + n] = acc[j][r];
    }
  }
}

// Finalize one step: sum 4 partials + Db (+Pred);
// FINAL: fp32 OutF[l][n]; else UTn[n][l] fp16 via LDS transpose.
template <int PRED, int FINAL>
__global__ __launch_bounds__(256) void iter_fin(
    const float* __restrict__ Part, const float* __restrict__ Db,
    const float* __restrict__ Pred, f16_t* __restrict__ UTn,
    float* __restrict__ OutF)
{
  const int L = 1024, Nn = 64;
  const int b = blockIdx.y, l0 = blockIdx.x * 64;
  const size_t base = ((size_t)b * L + l0) * Nn;
  const size_t ksStride = (size_t)8 * L * Nn;
  Db += base;
  if (PRED) Pred += base;

  __shared__ f16_t OutS[64 * 72];
  const int tid = threadIdx.x;

#pragma unroll
  for (int it = 0; it < 4; ++it) {
    const int idx = it * 256 + tid;
    const int l = idx >> 4, n4 = (idx & 15) * 4;
    const size_t o = (size_t)l * Nn + n4;
    float4 v = *(const float4*)(Part + base + o);
    const float4 p1 = *(const float4*)(Part + base + ksStride + o);
    const float4 p2 = *(const float4*)(Part + base + 2 * ksStride + o);
    const float4 p3 = *(const float4*)(Part + base + 3 * ksStride + o);
    v.x += p1.x; v.y += p1.y; v.z += p1.z; v.w += p1.w;
    v.x += p2.x; v.y += p2.y; v.z += p2.z; v.w += p2.w;
    v.x += p3.x; v.y += p3.y; v.z += p3.z; v.w += p3.w;
    const float4 d = *(const float4*)(Db + o);
    v.x += d.x; v.y += d.y; v.z += d.z; v.w += d.w;
    if (PRED) {
      const float4 p = *(const float4*)(Pred + o);
      v.x += p.x; v.y += p.y; v.z += p.z; v.w += p.w;
    }
    if (FINAL) {
      *(float4*)(OutF + base + o) = v;
    } else {
      OutS[(n4 + 0) * 72 + l] = (f16_t)v.x;
      OutS[(n4 + 1) * 72 + l] = (f16_t)v.y;
      OutS[(n4 + 2) * 72 + l] = (f16_t)v.z;
      OutS[(n4 + 3) * 72 + l] = (f16_t)v.w;
    }
  }
  if (!FINAL) {
    __syncthreads();
    f16_t* dst = UTn + (size_t)b * Nn * L;
#pragma unroll
    for (int it = 0; it < 2; ++it) {
      const int c = it * 256 + tid;
      const int n = c >> 3, lc = (c & 7) * 8;
      *(f16x8*)(dst + (size_t)n * L + l0 + lc) = *(const f16x8*)&OutS[n * 72 + lc];
    }
  }
}

extern "C" void kernel_launch(void* const* d_in, const int* in_sizes, int n_in,
                              void* d_out, int out_size, void* d_ws, size_t ws_size,
                              hipStream_t stream) {
  const float* samples = (const float*)d_in[0];  // [8,1024,3072]
  const float* label   = (const float*)d_in[1];  // [8,1024,64]
  const float* predict = (const float*)d_in[2];  // [8,1024,64]
  const float* W       = (const float*)d_in[3];  // [1024,3072]
  const float* bproj   = (const float*)d_in[4];  // [1024]
  float* out = (float*)d_out;                    // [8,1024,64]

  char* ws = (char*)d_ws;
  // region A [0, 12.58 MB): Whi/Wlo during projection; small buffers after
  f16_t* Whi = (f16_t*)ws;
  f16_t* Wlo = (f16_t*)(ws + 6291456);
  float* mx  = (float*)ws;                       // after gemm1 (W dead)
  float* inv = (float*)(ws + 32768);
  float* Db  = (float*)(ws + 65536);             // 2 MB
  f16_t* DbT = (f16_t*)(ws + 65536 + 2097152);   // 1 MB
  f16_t* UTa = (f16_t*)(ws + 65536 + 3145728);   // 1 MB
  f16_t* UTb = (f16_t*)(ws + 65536 + 4194304);   // 1 MB
  // region B [12.58, 62.9 MB): SampH (50 MB) during gemm1; G (32 MB) after
  f16_t* SampH = (f16_t*)(ws + 12582912);
  float* G     = (float*)(ws + 12582912);
  // region C [62.9, 96.5 MB): Shi/Slo; At aliases Shi, Part aliases Slo
  f16_t* Shi = (f16_t*)(ws + 62914560);
  f16_t* Slo = (f16_t*)(ws + 62914560 + 16777216);
  f16_t* At  = Shi;
  float* Part = (float*)Slo;                     // 8 MB (Slo dead after gemm2)

  const long long LH = 1024LL * 1024;
  const long long LL = 1024LL * 1024;

  // 0) prep: W split + samples convert (fused)
  prep_kernel<<<dim3(27648), 256, 0, stream>>>(W, Whi, Wlo, samples, SampH);

  // 1) S = samples @ W^T + b; epilogue x(1/32)+bias, split-store hi/lo
  gemm_mfma<0><<<dim3(8, 64, 1), 256, 0, stream>>>(
      SampH, Whi, Wlo, bproj, nullptr, Shi, Slo,
      8192, 1024, 3072, 0, 0, 0, 1.0f / 32.0f);

  // 2) G = S S^T - 1e5 I per batch, lower-triangle tiles + mirror
  gemm_mfma<1><<<dim3(36, 1, 8), 256, 0, stream>>>(
      Shi, Shi, Slo, nullptr, G, nullptr, nullptr,
      1024, 1024, 1024, LH, LH, LL, 1.0f);

  // 3) row stats, then At = softmax^T fp16 with column stats (Shi dead)
  rowstats_kernel<<<8192, 256, 0, stream>>>(G, mx, inv);
  make_at_kernel<<<8192, 256, 0, stream>>>(G, mx, inv, At);

  // 4) Db fp32 + DbT fp16 (fused)
  make_db_kernel<<<8, 1024, 0, stream>>>(label, Db, DbT);

  // 5) power iteration: each step = split-K partial + finalize
  dim3 gp(16, 8, 4), gf(16, 8);
  iter_part<<<gp, 256, 0, stream>>>(At, DbT, Part);                     // t=2
  iter_fin<0, 0><<<gf, 256, 0, stream>>>(Part, Db, nullptr, UTa, nullptr);
  iter_part<<<gp, 256, 0, stream>>>(At, UTa, Part);                     // t=3
  iter_fin<1, 0><<<gf, 256, 0, stream>>>(Part, Db, predict, UTb, nullptr);
  iter_part<<<gp, 256, 0, stream>>>(At, UTb, Part);                     // t=4
  iter_fin<0, 0><<<gf, 256, 0, stream>>>(Part, Db, nullptr, UTa, nullptr);
  iter_part<<<gp, 256, 0, stream>>>(At, UTa, Part);                     // t=5
  iter_fin<0, 0><<<gf, 256, 0, stream>>>(Part, Db, nullptr, UTb, nullptr);
  iter_part<<<gp, 256, 0, stream>>>(At, UTb, Part);                     // t=6
  iter_fin<0, 1><<<gf, 256, 0, stream>>>(Part, Db, nullptr, nullptr, out);
}